// Round 2
// baseline (1115.641 us; speedup 1.0000x reference)
//
#include <hip/hip_runtime.h>

// ---------------------------------------------------------------------------
// SpectralDistanceAttentionLayer — fp32 baseline (round 1 = round 0 resubmit;
// rounds 0-1 never ran: GPU broker at capacity both times)
// Pipeline:
//   1) qkv_k      : Q/K/V = x @ {Wq,Wk,Wv} + b           (tiled fp32 GEMM, fused)
//   2) flash_k    : fused scores*dist + spec-bias + online softmax + PV,
//                   split-K over 8 chunks -> partial (m, l, acc)
//   3) combine_k  : merge split-K partials -> attn_out
//   4) gemm_k<2>  : attn_out @ Wo + bo + x  -> tmp1
//   5) ln_k       : LN(tmp1; g1,b1) -> h
//   6) gemm_k<3>  : relu(h @ W1 + bf1) -> ffn1
//   7) gemm_k<2>  : ffn1 @ W2 + bf2 + h -> tmp2
//   8) ln_k       : LN(tmp2; g2,b2) -> d_out
// ---------------------------------------------------------------------------

constexpr int B   = 2;
constexpr int S   = 2048;
constexpr int D   = 256;
constexpr int H   = 8;
constexpr int DK  = 32;
constexpr int DFF = 1024;
constexpr int NS  = 16;

constexpr int QT  = 32;    // q rows per block (flash)
constexpr int KT  = 16;    // k tile (flash)
constexpr int KCH = 8;     // split-K chunks
constexpr int SKC = S / KCH;  // 256 keys per block

constexpr float RSDK   = 0.17677669529663687f;  // 1/sqrt(32)
constexpr float LN_EPS = 1e-5f;

// ---------------------------------------------------------------------------
// Generic 64x64-tile fp32 GEMM:  C[M][N] = A[M][K] @ W[K][N]  (+epilogue)
// EPI: 1 = +bias ; 2 = +bias +res ; 3 = +bias, relu
// ---------------------------------------------------------------------------
template <int EPI>
__device__ __forceinline__ void gemm_tile(
    const float* __restrict__ A, const float* __restrict__ W,
    const float* __restrict__ bias, const float* __restrict__ res,
    float* __restrict__ C, int M, int N, int Kd, int bm, int bn)
{
    __shared__ __align__(16) float As[16][68];
    __shared__ __align__(16) float Bs[16][64];

    const int tid = threadIdx.x;
    const int tx = tid & 15, ty = tid >> 4;

    const int am  = tid >> 2;   // 0..63  (A row within tile)
    const int ak4 = tid & 3;    // 0..3   (A k-chunk)
    const int bk  = tid >> 4;   // 0..15  (B k row)
    const int bn4 = tid & 15;   // 0..15  (B n-chunk)

    float acc[4][4] = {};

    for (int k0 = 0; k0 < Kd; k0 += 16) {
        __syncthreads();
        // stage A (transposed to As[k][m]) and B
        const float4 av = *(const float4*)&A[(size_t)(bm + am) * Kd + k0 + ak4 * 4];
        As[ak4 * 4 + 0][am] = av.x;
        As[ak4 * 4 + 1][am] = av.y;
        As[ak4 * 4 + 2][am] = av.z;
        As[ak4 * 4 + 3][am] = av.w;
        *(float4*)&Bs[bk][bn4 * 4] = *(const float4*)&W[(size_t)(k0 + bk) * N + bn + bn4 * 4];
        __syncthreads();

#pragma unroll
        for (int kk = 0; kk < 16; ++kk) {
            const float4 a4 = *(const float4*)&As[kk][ty * 4];
            const float4 b4 = *(const float4*)&Bs[kk][tx * 4];
            const float a[4] = {a4.x, a4.y, a4.z, a4.w};
            const float b[4] = {b4.x, b4.y, b4.z, b4.w};
#pragma unroll
            for (int i = 0; i < 4; ++i)
#pragma unroll
                for (int j = 0; j < 4; ++j)
                    acc[i][j] += a[i] * b[j];
        }
    }

#pragma unroll
    for (int i = 0; i < 4; ++i) {
        const int row = bm + ty * 4 + i;
        float o[4] = {acc[i][0], acc[i][1], acc[i][2], acc[i][3]};
        if (EPI >= 1) {
            const float4 bb = *(const float4*)&bias[bn + tx * 4];
            o[0] += bb.x; o[1] += bb.y; o[2] += bb.z; o[3] += bb.w;
        }
        if (EPI == 2) {
            const float4 rr = *(const float4*)&res[(size_t)row * N + bn + tx * 4];
            o[0] += rr.x; o[1] += rr.y; o[2] += rr.z; o[3] += rr.w;
        }
        if (EPI == 3) {
#pragma unroll
            for (int j = 0; j < 4; ++j) o[j] = fmaxf(o[j], 0.f);
        }
        float4 ov = {o[0], o[1], o[2], o[3]};
        *(float4*)&C[(size_t)row * N + bn + tx * 4] = ov;
    }
}

template <int EPI>
__global__ __launch_bounds__(256) void gemm_k(
    const float* __restrict__ A, const float* __restrict__ W,
    const float* __restrict__ bias, const float* __restrict__ res,
    float* __restrict__ C, int M, int N, int Kd)
{
    gemm_tile<EPI>(A, W, bias, res, C, M, N, Kd, blockIdx.y * 64, blockIdx.x * 64);
}

// fused QKV: blockIdx.z picks {Wq,Wk,Wv}
__global__ __launch_bounds__(256) void qkv_k(
    const float* __restrict__ x,
    const float* __restrict__ Wq, const float* __restrict__ bq,
    const float* __restrict__ Wk, const float* __restrict__ bk_,
    const float* __restrict__ Wv, const float* __restrict__ bv,
    float* __restrict__ Qo, float* __restrict__ Ko, float* __restrict__ Vo)
{
    const int which = blockIdx.z;
    const float* W  = (which == 0) ? Wq : (which == 1) ? Wk : Wv;
    const float* bb = (which == 0) ? bq : (which == 1) ? bk_ : bv;
    float* Cc       = (which == 0) ? Qo : (which == 1) ? Ko : Vo;
    gemm_tile<1>(x, W, bb, nullptr, Cc, B * S, D, D, blockIdx.y * 64, blockIdx.x * 64);
}

// ---------------------------------------------------------------------------
// Flash attention with split-K, fused dist-weighting + spectral bias + mask.
// grid = (KCH, S/QT, B), block = 256 (4 waves). Lane owns one (q, h) pair:
//   q = lane&31, h = wave*2 + (lane>>5).
// ---------------------------------------------------------------------------
__global__ __launch_bounds__(256) void flash_k(
    const float* __restrict__ Qg, const float* __restrict__ Kg, const float* __restrict__ Vg,
    const float* __restrict__ dist, const float* __restrict__ spec,
    const float* __restrict__ Wsp, const unsigned char* __restrict__ mask,
    float* __restrict__ pacc, float* __restrict__ pml)
{
    const int chunk = blockIdx.x;
    const int q0    = blockIdx.y * QT;
    const int b     = blockIdx.z;
    const int tid   = threadIdx.x;
    const int wv    = tid >> 6;
    const int lane  = tid & 63;
    const int q     = lane & 31;
    const int h     = wv * 2 + (lane >> 5);

    __shared__ __align__(16) float Kl[KT * D];          // 16 KB
    __shared__ __align__(16) float Vl[KT * D];          // 16 KB
    __shared__ float biasl[H][QT][KT + 1];              // 17.4 KB
    __shared__ float distl[QT][KT + 1];                 // 2.2 KB
    __shared__ float maskl[KT];
    __shared__ float wspl[NS * H];                      // 128 floats

    if (tid < NS * H) wspl[tid] = Wsp[tid];

    // Q fragment for this lane (32 floats)
    float qreg[DK];
    {
        const float* qp = Qg + ((size_t)(b * S + q0 + q) * D + h * DK);
#pragma unroll
        for (int i = 0; i < 8; ++i) {
            const float4 f = *(const float4*)(qp + i * 4);
            qreg[i * 4 + 0] = f.x; qreg[i * 4 + 1] = f.y;
            qreg[i * 4 + 2] = f.z; qreg[i * 4 + 3] = f.w;
        }
    }

    float mrun = -1e30f, lrun = 0.f;
    float acc[DK] = {};

    for (int t = 0; t < SKC / KT; ++t) {
        const int k0 = chunk * SKC + t * KT;
        __syncthreads();   // previous tile's LDS reads complete

        // ---- stage K, V (KT*D floats each; 4 float4 per thread per array)
        {
            const float* ksrc = Kg + (size_t)(b * S + k0) * D;
            const float* vsrc = Vg + (size_t)(b * S + k0) * D;
#pragma unroll
            for (int i = 0; i < 4; ++i) {
                const int idx = (i * 256 + tid) * 4;
                *(float4*)&Kl[idx] = *(const float4*)&ksrc[idx];
                *(float4*)&Vl[idx] = *(const float4*)&vsrc[idx];
            }
        }
        // ---- stage dist tile (QT x KT)
        if (tid < 128) {
            const int q_ = tid >> 2, k4 = (tid & 3) * 4;
            const float4 f = *(const float4*)&dist[(size_t)(b * S + q0 + q_) * S + k0 + k4];
            distl[q_][k4 + 0] = f.x; distl[q_][k4 + 1] = f.y;
            distl[q_][k4 + 2] = f.z; distl[q_][k4 + 3] = f.w;
        }
        if (tid < KT) maskl[tid] = mask[b * S + k0 + tid] ? 1.f : 0.f;

        // ---- spectral bias: 2 positions per thread; bias[h'] = sum_c spec*Wsp
        {
            float sp[2][NS];
#pragma unroll
            for (int pi = 0; pi < 2; ++pi) {
                const int p  = pi * 256 + tid;
                const int q_ = p >> 4, k_ = p & 15;
                const float* spp = spec + ((size_t)(b * S + q0 + q_) * S + (k0 + k_)) * NS;
#pragma unroll
                for (int c4 = 0; c4 < 4; ++c4) {
                    const float4 f = *(const float4*)(spp + c4 * 4);
                    sp[pi][c4 * 4 + 0] = f.x; sp[pi][c4 * 4 + 1] = f.y;
                    sp[pi][c4 * 4 + 2] = f.z; sp[pi][c4 * 4 + 3] = f.w;
                }
            }
            float bh[2][H] = {};
#pragma unroll
            for (int c = 0; c < NS; ++c)
#pragma unroll
                for (int h2 = 0; h2 < H; ++h2) {
                    const float wvv = wspl[c * H + h2];   // LDS broadcast
                    bh[0][h2] += sp[0][c] * wvv;
                    bh[1][h2] += sp[1][c] * wvv;
                }
#pragma unroll
            for (int pi = 0; pi < 2; ++pi) {
                const int p  = pi * 256 + tid;
                const int q_ = p >> 4, k_ = p & 15;
#pragma unroll
                for (int h2 = 0; h2 < H; ++h2) biasl[h2][q_][k_] = bh[pi][h2];
            }
        }
        __syncthreads();

        // ---- scores for this lane's (q,h): 16 keys
        float sv[KT];
        float tmax = -1e30f;
#pragma unroll
        for (int k = 0; k < KT; ++k) {
            const float* kp = &Kl[k * D + h * DK];
            float dot = 0.f;
#pragma unroll
            for (int d4 = 0; d4 < 8; ++d4) {
                const float4 kf = *(const float4*)(kp + d4 * 4);
                dot += qreg[d4 * 4 + 0] * kf.x + qreg[d4 * 4 + 1] * kf.y
                     + qreg[d4 * 4 + 2] * kf.z + qreg[d4 * 4 + 3] * kf.w;
            }
            float s = dot * RSDK * distl[q][k] + biasl[h][q][k];
            s = (maskl[k] != 0.f) ? -1e30f : s;
            sv[k] = s;
            tmax = fmaxf(tmax, s);
        }
        // ---- online softmax update
        const float mnew  = fmaxf(mrun, tmax);
        const float scale = __expf(mrun - mnew);
        lrun *= scale;
#pragma unroll
        for (int d = 0; d < DK; ++d) acc[d] *= scale;
#pragma unroll
        for (int k = 0; k < KT; ++k) {
            const float p = __expf(sv[k] - mnew);
            lrun += p;
            const float* vp = &Vl[k * D + h * DK];
#pragma unroll
            for (int d4 = 0; d4 < 8; ++d4) {
                const float4 vf = *(const float4*)(vp + d4 * 4);
                acc[d4 * 4 + 0] += p * vf.x; acc[d4 * 4 + 1] += p * vf.y;
                acc[d4 * 4 + 2] += p * vf.z; acc[d4 * 4 + 3] += p * vf.w;
            }
        }
        mrun = mnew;
    }

    // ---- write split-K partials
    const size_t idx = ((size_t)(b * KCH + chunk) * S + (q0 + q)) * H + h;
    pml[idx * 2 + 0] = mrun;
    pml[idx * 2 + 1] = lrun;
    float* pa = pacc + idx * DK;
#pragma unroll
    for (int d4 = 0; d4 < 8; ++d4) {
        float4 f = {acc[d4 * 4 + 0], acc[d4 * 4 + 1], acc[d4 * 4 + 2], acc[d4 * 4 + 3]};
        *(float4*)(pa + d4 * 4) = f;
    }
}

// merge split-K partials -> attn_out (B,S,D)
__global__ __launch_bounds__(256) void combine_k(
    const float* __restrict__ pacc, const float* __restrict__ pml,
    float* __restrict__ out)
{
    const int o  = blockIdx.x * 256 + threadIdx.x;   // (qg*H + h)*32 + d
    const int d  = o & 31;
    const int h  = (o >> 5) & 7;
    const int qg = o >> 8;                            // b*S + q
    const int b  = qg >> 11, qq = qg & (S - 1);

    float m[KCH], l[KCH];
    float M = -1e30f;
#pragma unroll
    for (int c = 0; c < KCH; ++c) {
        const size_t id = ((size_t)(b * KCH + c) * S + qq) * H + h;
        m[c] = pml[id * 2 + 0];
        l[c] = pml[id * 2 + 1];
        M = fmaxf(M, m[c]);
    }
    float num = 0.f, den = 0.f;
#pragma unroll
    for (int c = 0; c < KCH; ++c) {
        const size_t id = ((size_t)(b * KCH + c) * S + qq) * H + h;
        const float w = __expf(m[c] - M);
        den += w * l[c];
        num += w * pacc[id * DK + d];
    }
    out[o] = num / fmaxf(den, 1e-30f);
}

// row LayerNorm over D=256, one block per row
__global__ __launch_bounds__(256) void ln_k(
    const float* __restrict__ in, const float* __restrict__ g,
    const float* __restrict__ bb, float* __restrict__ out)
{
    const int row = blockIdx.x;
    const int t   = threadIdx.x;
    const float v = in[(size_t)row * D + t];
    float s1 = v, s2 = v * v;
#pragma unroll
    for (int off = 32; off >= 1; off >>= 1) {
        s1 += __shfl_xor(s1, off);
        s2 += __shfl_xor(s2, off);
    }
    __shared__ float a1[4], a2[4];
    if ((t & 63) == 0) { a1[t >> 6] = s1; a2[t >> 6] = s2; }
    __syncthreads();
    const float S1 = a1[0] + a1[1] + a1[2] + a1[3];
    const float S2 = a2[0] + a2[1] + a2[2] + a2[3];
    const float mu  = S1 * (1.f / D);
    const float var = S2 * (1.f / D) - mu * mu;
    out[(size_t)row * D + t] = (v - mu) * rsqrtf(var + LN_EPS) * g[t] + bb[t];
}

// ---------------------------------------------------------------------------
extern "C" void kernel_launch(void* const* d_in, const int* in_sizes, int n_in,
                              void* d_out, int out_size, void* d_ws, size_t ws_size,
                              hipStream_t stream)
{
    const float* x    = (const float*)d_in[0];
    const float* dist = (const float*)d_in[1];
    const float* spec = (const float*)d_in[2];
    const float* Wq   = (const float*)d_in[3];
    const float* bq   = (const float*)d_in[4];
    const float* Wk   = (const float*)d_in[5];
    const float* bk_  = (const float*)d_in[6];
    const float* Wv   = (const float*)d_in[7];
    const float* bv   = (const float*)d_in[8];
    const float* Wo   = (const float*)d_in[9];
    const float* bo   = (const float*)d_in[10];
    const float* Wsp  = (const float*)d_in[11];
    const float* g1   = (const float*)d_in[12];
    const float* b1   = (const float*)d_in[13];
    const float* g2   = (const float*)d_in[14];
    const float* b2   = (const float*)d_in[15];
    const float* W1   = (const float*)d_in[16];
    const float* bf1  = (const float*)d_in[17];
    const float* W2   = (const float*)d_in[18];
    const float* bf2  = (const float*)d_in[19];
    const unsigned char* mask = (const unsigned char*)d_in[20];

    float* outp = (float*)d_out;

    // workspace layout (floats)
    float* w = (float*)d_ws;
    const size_t NBSD = (size_t)B * S * D;                  // 1,048,576
    float* Qb   = w;
    float* Kb   = w + NBSD;
    float* Vb   = w + 2 * NBSD;
    float* pacc = w + 3 * NBSD;                             // 8,388,608 floats
    float* pml  = pacc + (size_t)B * KCH * S * H * DK;      // 1,048,576 floats
    // aliases (regions dead by the time these are written)
    float* attn = Qb;
    float* tmp1 = Kb;
    float* hbuf = Vb;
    float* ffn1 = pacc;
    float* tmp2 = pacc + (size_t)B * S * DFF;

    const int M = B * S;   // 4096

    // 1) QKV projection (fused 3-way)
    qkv_k<<<dim3(D / 64, M / 64, 3), 256, 0, stream>>>(x, Wq, bq, Wk, bk_, Wv, bv, Qb, Kb, Vb);

    // 2) flash attention (split-K partials)
    flash_k<<<dim3(KCH, S / QT, B), 256, 0, stream>>>(Qb, Kb, Vb, dist, spec, Wsp, mask, pacc, pml);

    // 3) combine partials
    combine_k<<<dim3((B * S * D) / 256), 256, 0, stream>>>(pacc, pml, attn);

    // 4) output projection + residual
    gemm_k<2><<<dim3(D / 64, M / 64), 256, 0, stream>>>(attn, Wo, bo, x, tmp1, M, D, D);

    // 5) LN1
    ln_k<<<dim3(M), 256, 0, stream>>>(tmp1, g1, b1, hbuf);

    // 6) FFN up + relu
    gemm_k<3><<<dim3(DFF / 64, M / 64), 256, 0, stream>>>(hbuf, W1, bf1, nullptr, ffn1, M, DFF, D);

    // 7) FFN down + residual
    gemm_k<2><<<dim3(D / 64, M / 64), 256, 0, stream>>>(ffn1, W2, bf2, hbuf, tmp2, M, D, DFF);

    // 8) LN2 -> output
    ln_k<<<dim3(M), 256, 0, stream>>>(tmp2, g2, b2, outp);
}